// Round 1
// baseline (786.972 us; speedup 1.0000x reference)
//
#include <hip/hip_runtime.h>
#include <stdint.h>

#define N_V 50000
#define F_DIM 128
#define K_DIM 128
#define H_DIM 3
#define M_DIM 10

using bf16x8 = __attribute__((ext_vector_type(8))) short;  // 8 bf16 = 4 VGPRs
using f32x4  = __attribute__((ext_vector_type(4))) float;

__device__ inline unsigned short f2bf(float f) {
    union { float f; uint32_t u; } v; v.f = f;
    uint32_t u = v.u;
    u += 0x7fffu + ((u >> 16) & 1u);   // round-to-nearest-even
    return (unsigned short)(u >> 16);
}

// ---------------------------------------------------------------------------
// Kernel 1: convert 9 weight matrices (H,F,K) fp32 -> bf16, transposed to
// Wt[b][k][f]  (b = 3*h + t; t: 0=Wvc 1=Wvn_int 2=Wvn_nh)
// so the GEMM's B-operand (col-major-in-k) staging is contiguous.
// ---------------------------------------------------------------------------
__global__ void prep_weights(const float* __restrict__ Wvc,
                             const float* __restrict__ Wvn_int,
                             const float* __restrict__ Wvn_nh,
                             unsigned short* __restrict__ Wt) {
    int idx = blockIdx.x * 256 + threadIdx.x;       // 0 .. 9*128*128-1
    if (idx >= 9 * 128 * 128) return;
    int b   = idx >> 14;          // /16384
    int rem = idx & 16383;
    int k = rem >> 7;
    int f = rem & 127;
    int h = b / 3, t = b - 3 * h;
    const float* src = (t == 0) ? Wvc : (t == 1) ? Wvn_int : Wvn_nh;
    Wt[idx] = f2bf(src[(h * 128 + f) * 128 + k]);
}

// ---------------------------------------------------------------------------
// Kernel 2: MFMA GEMM. Grid = (ceil(N/64), 9). Block = 256 thr (4 waves).
// Block computes C-tile 64 rows x 128 cols for weight-block b.
// Full K (=F=128) staged once into LDS (no K-tile loop).
// Epilogue: t==0 -> Zc into d_out fp32 + e_center dot(a_c)
//           t==1 -> Vint bf16 + e_int dot(a_n)
//           t==2 -> Vnh  bf16 + e_nh  dot(a_n)
// ---------------------------------------------------------------------------
#define BM 64
#define LDA 136   // padded bf16 stride (272 B -> 2-way bank aliasing = free)

__global__ __launch_bounds__(256, 2) void gemm_kernel(
    const float* __restrict__ X,            // N_V x 128 fp32
    const unsigned short* __restrict__ Wt,  // 9 x 128(k) x 128(f) bf16
    const float* __restrict__ a,            // H x 256
    float* __restrict__ out,                // N_V x 384
    unsigned short* __restrict__ Vint,      // H*N_V*128 bf16
    unsigned short* __restrict__ Vnh,       // H*N_V*128 bf16
    float* __restrict__ e_center,           // H*N_V
    float* __restrict__ e_int,
    float* __restrict__ e_nh) {
    __shared__ unsigned short As[BM * LDA];    // rows x f  (17408 B)
    __shared__ unsigned short Bs[128 * LDA];   // col  x f  (34816 B)

    const int tid    = threadIdx.x;
    const int b      = blockIdx.y;
    const int h      = b / 3;
    const int t      = b - 3 * h;
    const int m_base = blockIdx.x * BM;

    // ---- stage A: 64 rows x 128 f (fp32 -> bf16). 2048 float4 chunks.
    const float4* Xv = (const float4*)X;
    #pragma unroll
    for (int i = 0; i < 8; ++i) {
        int idx = i * 256 + tid;        // 0..2047
        int r   = idx >> 5;             // 32 float4 per row
        int c4  = idx & 31;
        int grow = m_base + r;
        float4 v;
        if (grow < N_V) v = Xv[grow * 32 + c4];
        else            v = make_float4(0.f, 0.f, 0.f, 0.f);
        ushort4 p;
        p.x = f2bf(v.x); p.y = f2bf(v.y); p.z = f2bf(v.z); p.w = f2bf(v.w);
        *(ushort4*)&As[r * LDA + c4 * 4] = p;
    }
    // ---- stage B: 128 cols x 128 f bf16 (already transposed). 2048 16B chunks.
    const int4* Wv = (const int4*)(Wt + b * 16384);
    #pragma unroll
    for (int i = 0; i < 8; ++i) {
        int idx = i * 256 + tid;        // 0..2047
        int col = idx >> 4;             // 16 chunks of 8 bf16 per col
        int c8  = idx & 15;
        int4 v = Wv[col * 16 + c8];
        *(int4*)&Bs[col * LDA + c8 * 8] = v;
    }
    __syncthreads();

    // ---- MFMA: wave w -> rows [w*16, w*16+16), all 128 cols
    const int wv   = tid >> 6;
    const int lane = tid & 63;
    const int q    = lane >> 4;
    const int ln   = lane & 15;
    const int m0   = wv * 16;

    f32x4 acc[8];
    #pragma unroll
    for (int f = 0; f < 8; ++f) acc[f] = (f32x4){0.f, 0.f, 0.f, 0.f};

    #pragma unroll
    for (int kk = 0; kk < 4; ++kk) {
        int k0 = kk * 32 + q * 8;
        bf16x8 afrag = *(const bf16x8*)&As[(m0 + ln) * LDA + k0];
        #pragma unroll
        for (int f = 0; f < 8; ++f) {
            bf16x8 bfrag = *(const bf16x8*)&Bs[(f * 16 + ln) * LDA + k0];
            acc[f] = __builtin_amdgcn_mfma_f32_16x16x32_bf16(afrag, bfrag, acc[f], 0, 0, 0);
        }
    }

    // ---- epilogue. C/D layout: row = q*4 + r, col = f*16 + ln.
    const float* a_vec = a + h * 256 + (t == 0 ? 128 : 0);
    float av[8];
    #pragma unroll
    for (int f = 0; f < 8; ++f) av[f] = a_vec[f * 16 + ln];

    float dot[4] = {0.f, 0.f, 0.f, 0.f};
    #pragma unroll
    for (int f = 0; f < 8; ++f)
        #pragma unroll
        for (int r = 0; r < 4; ++r) dot[r] += acc[f][r] * av[f];
    // reduce over the 16 lanes that share q (lanes differing in low 4 bits)
    #pragma unroll
    for (int off = 1; off < 16; off <<= 1)
        #pragma unroll
        for (int r = 0; r < 4; ++r) dot[r] += __shfl_xor(dot[r], off, 64);

    float* e_arr = (t == 0) ? e_center : (t == 1) ? e_int : e_nh;
    if (ln == 0) {
        #pragma unroll
        for (int r = 0; r < 4; ++r) {
            int grow = m_base + m0 + q * 4 + r;
            if (grow < N_V) e_arr[h * N_V + grow] = dot[r];
        }
    }

    unsigned short* Vside = (t == 1) ? Vint : Vnh;
    #pragma unroll
    for (int f = 0; f < 8; ++f) {
        int col = f * 16 + ln;
        #pragma unroll
        for (int r = 0; r < 4; ++r) {
            int grow = m_base + m0 + q * 4 + r;
            if (grow >= N_V) continue;
            float v = acc[f][r];
            if (t == 0) out[(size_t)grow * 384 + h * 128 + col] = v;
            else        Vside[((size_t)h * N_V + grow) * 128 + col] = f2bf(v);
        }
    }
}

// ---------------------------------------------------------------------------
// Kernel 3: attention + epilogue. One wave per vertex n; lane holds cols
// 2*lane, 2*lane+1. Loops h=0..2 internally (reuses index/edge loads).
// ---------------------------------------------------------------------------
__device__ inline float2 branch10(const int* j, const float* w,
                                  const float* __restrict__ es,
                                  const unsigned short* __restrict__ V,
                                  float ec, int lane) {
    float lg[M_DIM];
    float mx = 0.f;   // masked entries have logit exactly 0, so mx >= 0 matches ref
    int cnt = 0;
    #pragma unroll
    for (int m = 0; m < M_DIM; ++m) {
        int jm = j[m];
        float l = 0.f;
        if (jm >= 0) { l = (es[jm] + ec) * w[m]; cnt++; }
        lg[m] = l;
        mx = fmaxf(mx, l);
    }
    // reference softmaxes over ALL M entries (masked ones contribute exp(0))
    float s = 0.f;
    #pragma unroll
    for (int m = 0; m < M_DIM; ++m) { lg[m] = __expf(lg[m] - mx); s += lg[m]; }
    float inv = 1.f / s;
    float ax = 0.f, ay = 0.f;
    #pragma unroll
    for (int m = 0; m < M_DIM; ++m) {
        int jm = j[m];
        if (jm < 0) continue;
        float alpha = lg[m] * inv;
        uint32_t pv = *(const uint32_t*)&V[(size_t)jm * 128 + lane * 2];
        union { uint32_t u; float f; } lo, hi;
        lo.u = pv << 16;
        hi.u = pv & 0xffff0000u;
        ax += alpha * lo.f;
        ay += alpha * hi.f;
    }
    float norm = (float)(cnt > 0 ? cnt : 1);
    return make_float2(ax / norm, ay / norm);
}

__global__ __launch_bounds__(256) void attn_kernel(
    const int* __restrict__ nh_idx, const int* __restrict__ int_idx,
    const float* __restrict__ nh_edge, const float* __restrict__ int_edge,
    const float* __restrict__ bv,
    const unsigned short* __restrict__ Vint, const unsigned short* __restrict__ Vnh,
    const float* __restrict__ e_center, const float* __restrict__ e_int,
    const float* __restrict__ e_nh,
    float* __restrict__ out) {
    const int wv   = threadIdx.x >> 6;
    const int lane = threadIdx.x & 63;
    const int n    = blockIdx.x * 4 + wv;
    if (n >= N_V) return;

    int ji[M_DIM], jn[M_DIM];
    float wi[M_DIM], wn[M_DIM];
    #pragma unroll
    for (int m = 0; m < M_DIM; ++m) {
        ji[m] = int_idx[n * M_DIM + m];
        wi[m] = int_edge[n * M_DIM + m];
        jn[m] = nh_idx[n * M_DIM + m];
        wn[m] = nh_edge[n * M_DIM + m];
    }

    #pragma unroll
    for (int h = 0; h < H_DIM; ++h) {
        float ec = e_center[h * N_V + n];
        float2 zi = branch10(ji, wi, e_int + (size_t)h * N_V,
                             Vint + (size_t)h * N_V * 128, ec, lane);
        float2 zn = branch10(jn, wn, e_nh + (size_t)h * N_V,
                             Vnh + (size_t)h * N_V * 128, ec, lane);
        size_t o = (size_t)n * 384 + h * 128 + lane * 2;
        float2 zc = *(const float2*)&out[o];
        float2 bb = *(const float2*)&bv[h * 128 + lane * 2];
        float o0 = zc.x + zi.x + zn.x + bb.x;
        float o1 = zc.y + zi.y + zn.y + bb.y;
        float2 res = make_float2(fmaxf(o0, 0.f), fmaxf(o1, 0.f));
        *(float2*)&out[o] = res;
    }
}

// ---------------------------------------------------------------------------
extern "C" void kernel_launch(void* const* d_in, const int* in_sizes, int n_in,
                              void* d_out, int out_size, void* d_ws, size_t ws_size,
                              hipStream_t stream) {
    const float* vertices    = (const float*)d_in[0];
    const int*   nh_indices  = (const int*)d_in[1];
    const int*   int_indices = (const int*)d_in[2];
    const float* nh_edges    = (const float*)d_in[3];
    const float* int_edges   = (const float*)d_in[4];
    // d_in[5] is_int: unused by the reference
    const float* Wvc     = (const float*)d_in[6];
    const float* bv      = (const float*)d_in[7];
    const float* Wvn_int = (const float*)d_in[8];
    const float* Wvn_nh  = (const float*)d_in[9];
    const float* a       = (const float*)d_in[10];
    float* out = (float*)d_out;

    char* ws = (char*)d_ws;
    size_t off = 0;
    unsigned short* Wt = (unsigned short*)(ws + off);
    off += (size_t)9 * 128 * 128 * 2;  off = (off + 255) & ~(size_t)255;
    unsigned short* Vint = (unsigned short*)(ws + off);
    off += (size_t)H_DIM * N_V * 128 * 2;  off = (off + 255) & ~(size_t)255;
    unsigned short* Vnh = (unsigned short*)(ws + off);
    off += (size_t)H_DIM * N_V * 128 * 2;  off = (off + 255) & ~(size_t)255;
    float* e_center = (float*)(ws + off);
    off += (size_t)H_DIM * N_V * 4;  off = (off + 255) & ~(size_t)255;
    float* e_int = (float*)(ws + off);
    off += (size_t)H_DIM * N_V * 4;  off = (off + 255) & ~(size_t)255;
    float* e_nh = (float*)(ws + off);
    off += (size_t)H_DIM * N_V * 4;

    prep_weights<<<(9 * 128 * 128 + 255) / 256, 256, 0, stream>>>(Wvc, Wvn_int, Wvn_nh, Wt);

    dim3 grid_g((N_V + BM - 1) / BM, 9);
    gemm_kernel<<<grid_g, 256, 0, stream>>>(vertices, Wt, a, out, Vint, Vnh,
                                            e_center, e_int, e_nh);

    attn_kernel<<<(N_V + 3) / 4, 256, 0, stream>>>(nh_indices, int_indices,
                                                   nh_edges, int_edges, bv,
                                                   Vint, Vnh, e_center, e_int,
                                                   e_nh, out);
}

// Round 2
// 303.872 us; speedup vs baseline: 2.5898x; 2.5898x over previous
//
#include <hip/hip_runtime.h>
#include <stdint.h>

#define N_V 50000
#define F_DIM 128
#define K_DIM 128
#define H_DIM 3
#define M_DIM 10

using bf16x8 = __attribute__((ext_vector_type(8))) short;  // 8 bf16 = 4 VGPRs
using f32x4  = __attribute__((ext_vector_type(4))) float;

__device__ inline unsigned short f2bf(float f) {
    union { float f; uint32_t u; } v; v.f = f;
    uint32_t u = v.u;
    u += 0x7fffu + ((u >> 16) & 1u);   // round-to-nearest-even
    return (unsigned short)(u >> 16);
}

// ---------------------------------------------------------------------------
// Kernel 1: convert 9 weight matrices (H,F,K) fp32 -> bf16, transposed to
// Wt[b][k][f]  (b = 3*h + t; t: 0=Wvc 1=Wvn_int 2=Wvn_nh)
// ---------------------------------------------------------------------------
__global__ void prep_weights(const float* __restrict__ Wvc,
                             const float* __restrict__ Wvn_int,
                             const float* __restrict__ Wvn_nh,
                             unsigned short* __restrict__ Wt) {
    int idx = blockIdx.x * 256 + threadIdx.x;       // 0 .. 9*128*128-1
    if (idx >= 9 * 128 * 128) return;
    int b   = idx >> 14;          // /16384
    int rem = idx & 16383;
    int k = rem >> 7;
    int f = rem & 127;
    int h = b / 3, t = b - 3 * h;
    const float* src = (t == 0) ? Wvc : (t == 1) ? Wvn_int : Wvn_nh;
    Wt[idx] = f2bf(src[(h * 128 + f) * 128 + k]);
}

// ---------------------------------------------------------------------------
// Kernel 2: MFMA GEMM. Grid = (ceil(N/64), 9). Block = 256 thr (4 waves).
// Block computes C-tile 64 rows x 128 cols for weight-block b.
// Epilogue: t==0 -> Zc into d_out fp32 + e_center dot(a_c)
//           t==1 -> Vint bf16 + e_int dot(a_n)
//           t==2 -> Vnh  bf16 + e_nh  dot(a_n)
// ---------------------------------------------------------------------------
#define BM 64
#define LDA 136   // padded bf16 stride (272 B -> 2-way bank aliasing = free)

__global__ __launch_bounds__(256, 2) void gemm_kernel(
    const float* __restrict__ X,            // N_V x 128 fp32
    const unsigned short* __restrict__ Wt,  // 9 x 128(k) x 128(f) bf16
    const float* __restrict__ a,            // H x 256
    float* __restrict__ out,                // N_V x 384
    unsigned short* __restrict__ Vint,      // H*N_V*128 bf16
    unsigned short* __restrict__ Vnh,       // H*N_V*128 bf16
    float* __restrict__ e_center,           // H*N_V
    float* __restrict__ e_int,
    float* __restrict__ e_nh) {
    __shared__ unsigned short As[BM * LDA];
    __shared__ unsigned short Bs[128 * LDA];

    const int tid    = threadIdx.x;
    const int b      = blockIdx.y;
    const int h      = b / 3;
    const int t      = b - 3 * h;
    const int m_base = blockIdx.x * BM;

    const float4* Xv = (const float4*)X;
    #pragma unroll
    for (int i = 0; i < 8; ++i) {
        int idx = i * 256 + tid;        // 0..2047
        int r   = idx >> 5;
        int c4  = idx & 31;
        int grow = m_base + r;
        float4 v;
        if (grow < N_V) v = Xv[grow * 32 + c4];
        else            v = make_float4(0.f, 0.f, 0.f, 0.f);
        ushort4 p;
        p.x = f2bf(v.x); p.y = f2bf(v.y); p.z = f2bf(v.z); p.w = f2bf(v.w);
        *(ushort4*)&As[r * LDA + c4 * 4] = p;
    }
    const int4* Wv = (const int4*)(Wt + b * 16384);
    #pragma unroll
    for (int i = 0; i < 8; ++i) {
        int idx = i * 256 + tid;
        int col = idx >> 4;
        int c8  = idx & 15;
        int4 v = Wv[col * 16 + c8];
        *(int4*)&Bs[col * LDA + c8 * 8] = v;
    }
    __syncthreads();

    const int wv   = tid >> 6;
    const int lane = tid & 63;
    const int q    = lane >> 4;
    const int ln   = lane & 15;
    const int m0   = wv * 16;

    f32x4 acc[8];
    #pragma unroll
    for (int f = 0; f < 8; ++f) acc[f] = (f32x4){0.f, 0.f, 0.f, 0.f};

    #pragma unroll
    for (int kk = 0; kk < 4; ++kk) {
        int k0 = kk * 32 + q * 8;
        bf16x8 afrag = *(const bf16x8*)&As[(m0 + ln) * LDA + k0];
        #pragma unroll
        for (int f = 0; f < 8; ++f) {
            bf16x8 bfrag = *(const bf16x8*)&Bs[(f * 16 + ln) * LDA + k0];
            acc[f] = __builtin_amdgcn_mfma_f32_16x16x32_bf16(afrag, bfrag, acc[f], 0, 0, 0);
        }
    }

    // epilogue. C/D layout: row = q*4 + r, col = f*16 + ln.
    const float* a_vec = a + h * 256 + (t == 0 ? 128 : 0);
    float av[8];
    #pragma unroll
    for (int f = 0; f < 8; ++f) av[f] = a_vec[f * 16 + ln];

    float dot[4] = {0.f, 0.f, 0.f, 0.f};
    #pragma unroll
    for (int f = 0; f < 8; ++f)
        #pragma unroll
        for (int r = 0; r < 4; ++r) dot[r] += acc[f][r] * av[f];
    #pragma unroll
    for (int off = 1; off < 16; off <<= 1)
        #pragma unroll
        for (int r = 0; r < 4; ++r) dot[r] += __shfl_xor(dot[r], off, 64);

    float* e_arr = (t == 0) ? e_center : (t == 1) ? e_int : e_nh;
    if (ln == 0) {
        #pragma unroll
        for (int r = 0; r < 4; ++r) {
            int grow = m_base + m0 + q * 4 + r;
            if (grow < N_V) e_arr[h * N_V + grow] = dot[r];
        }
    }

    unsigned short* Vside = (t == 1) ? Vint : Vnh;
    #pragma unroll
    for (int f = 0; f < 8; ++f) {
        int col = f * 16 + ln;
        #pragma unroll
        for (int r = 0; r < 4; ++r) {
            int grow = m_base + m0 + q * 4 + r;
            if (grow >= N_V) continue;
            float v = acc[f][r];
            if (t == 0) out[(size_t)grow * 384 + h * 128 + col] = v;
            else        Vside[((size_t)h * N_V + grow) * 128 + col] = f2bf(v);
        }
    }
}

// ---------------------------------------------------------------------------
// Kernel 3: attention. One wave per vertex. Wave = 4 groups x 16 lanes.
// Logit phase: lanes 0-9 do int-branch logits, lanes 16-25 nh-branch,
// softmax via 16-lane shfl_xor reductions; alpha/(s*norm) folded into one
// per-row coefficient. Gather phase: group g gathers full 256B rows via
// dwordx4 (8 bf16/lane): groups 0,1 -> int rows 0-4/5-9, groups 2,3 -> nh.
// Cross-group xor-reduce (16,32) sums both branches. Epilogue fused.
// ---------------------------------------------------------------------------
__global__ __launch_bounds__(256) void attn_kernel(
    const int* __restrict__ nh_idx, const int* __restrict__ int_idx,
    const float* __restrict__ nh_edge, const float* __restrict__ int_edge,
    const float* __restrict__ bv,
    const unsigned short* __restrict__ Vint, const unsigned short* __restrict__ Vnh,
    const float* __restrict__ e_center, const float* __restrict__ e_int,
    const float* __restrict__ e_nh,
    float* __restrict__ out) {
    const int wv   = threadIdx.x >> 6;
    const int lane = threadIdx.x & 63;
    const int n    = blockIdx.x * 4 + wv;
    if (n >= N_V) return;
    const int g  = lane >> 4;
    const int gl = lane & 15;

    const bool part = (g <= 1) && (gl < M_DIM);
    int jm = -1; float wm = 0.f;
    if (part) {
        const int*   idx = (g == 0) ? int_idx  : nh_idx;
        const float* ed  = (g == 0) ? int_edge : nh_edge;
        jm = idx[n * M_DIM + gl];
        wm = ed[n * M_DIM + gl];
    }
    const bool  valid = part && (jm >= 0);
    const int   jc    = valid ? jm : 0;
    const float vfl   = valid ? 1.f : 0.f;

    #pragma unroll
    for (int h = 0; h < H_DIM; ++h) {
        float ec = e_center[h * N_V + n];

        // ---- logits (lanes 0-9: int, 16-25: nh). masked entries logit = 0.
        float l = -3.0e38f;
        if (part) {
            const float* es = (g == 0) ? (e_int + (size_t)h * N_V)
                                       : (e_nh  + (size_t)h * N_V);
            float e = es[jc];
            l = valid ? (e + ec) * wm : 0.f;
        }
        float mx = l;
        #pragma unroll
        for (int off = 1; off < 16; off <<= 1) mx = fmaxf(mx, __shfl_xor(mx, off, 64));
        float ex = part ? __expf(l - mx) : 0.f;
        float sv = ex, cf = vfl;
        #pragma unroll
        for (int off = 1; off < 16; off <<= 1) {
            sv += __shfl_xor(sv, off, 64);
            cf += __shfl_xor(cf, off, 64);
        }
        float alphap = 0.f;
        if (valid) alphap = ex / (sv * fmaxf(cf, 1.f));   // alpha/norm folded

        // ---- gather: group g handles 5 rows of its branch
        const unsigned short* Vb = (g < 2) ? (Vint + (size_t)h * N_V * 128)
                                           : (Vnh  + (size_t)h * N_V * 128);
        const int src_base = (g < 2 ? 0 : 16) + (g & 1) * 5;
        float acc[8] = {0.f, 0.f, 0.f, 0.f, 0.f, 0.f, 0.f, 0.f};
        #pragma unroll
        for (int i = 0; i < 5; ++i) {
            int   src = src_base + i;
            int   j   = __shfl(jc, src, 64);
            float al  = __shfl(alphap, src, 64);
            uint4 pv  = *(const uint4*)&Vb[(size_t)j * 128 + gl * 8];
            uint32_t w4[4] = {pv.x, pv.y, pv.z, pv.w};
            #pragma unroll
            for (int c = 0; c < 4; ++c) {
                union { uint32_t u; float f; } lo, hi;
                lo.u = w4[c] << 16;
                hi.u = w4[c] & 0xffff0000u;
                acc[2 * c]     += al * lo.f;
                acc[2 * c + 1] += al * hi.f;
            }
        }
        // ---- cross-group reduce: sums int + nh branches
        #pragma unroll
        for (int c = 0; c < 8; ++c) {
            acc[c] += __shfl_xor(acc[c], 16, 64);
            acc[c] += __shfl_xor(acc[c], 32, 64);
        }
        // ---- fused epilogue: groups 0,1 write 4 floats each (float4)
        if (g < 2) {
            size_t o = (size_t)n * 384 + h * 128 + gl * 8 + g * 4;
            float4 zc = *(const float4*)&out[o];
            float4 bb = *(const float4*)&bv[h * 128 + gl * 8 + g * 4];
            float4 zn;
            if (g == 0) zn = make_float4(acc[0], acc[1], acc[2], acc[3]);
            else        zn = make_float4(acc[4], acc[5], acc[6], acc[7]);
            float4 r;
            r.x = fmaxf(zc.x + zn.x + bb.x, 0.f);
            r.y = fmaxf(zc.y + zn.y + bb.y, 0.f);
            r.z = fmaxf(zc.z + zn.z + bb.z, 0.f);
            r.w = fmaxf(zc.w + zn.w + bb.w, 0.f);
            *(float4*)&out[o] = r;
        }
    }
}

// ---------------------------------------------------------------------------
extern "C" void kernel_launch(void* const* d_in, const int* in_sizes, int n_in,
                              void* d_out, int out_size, void* d_ws, size_t ws_size,
                              hipStream_t stream) {
    const float* vertices    = (const float*)d_in[0];
    const int*   nh_indices  = (const int*)d_in[1];
    const int*   int_indices = (const int*)d_in[2];
    const float* nh_edges    = (const float*)d_in[3];
    const float* int_edges   = (const float*)d_in[4];
    // d_in[5] is_int: unused by the reference
    const float* Wvc     = (const float*)d_in[6];
    const float* bv      = (const float*)d_in[7];
    const float* Wvn_int = (const float*)d_in[8];
    const float* Wvn_nh  = (const float*)d_in[9];
    const float* a       = (const float*)d_in[10];
    float* out = (float*)d_out;

    char* ws = (char*)d_ws;
    size_t off = 0;
    unsigned short* Wt = (unsigned short*)(ws + off);
    off += (size_t)9 * 128 * 128 * 2;  off = (off + 255) & ~(size_t)255;
    unsigned short* Vint = (unsigned short*)(ws + off);
    off += (size_t)H_DIM * N_V * 128 * 2;  off = (off + 255) & ~(size_t)255;
    unsigned short* Vnh = (unsigned short*)(ws + off);
    off += (size_t)H_DIM * N_V * 128 * 2;  off = (off + 255) & ~(size_t)255;
    float* e_center = (float*)(ws + off);
    off += (size_t)H_DIM * N_V * 4;  off = (off + 255) & ~(size_t)255;
    float* e_int = (float*)(ws + off);
    off += (size_t)H_DIM * N_V * 4;  off = (off + 255) & ~(size_t)255;
    float* e_nh = (float*)(ws + off);
    off += (size_t)H_DIM * N_V * 4;

    prep_weights<<<(9 * 128 * 128 + 255) / 256, 256, 0, stream>>>(Wvc, Wvn_int, Wvn_nh, Wt);

    dim3 grid_g((N_V + BM - 1) / BM, 9);
    gemm_kernel<<<grid_g, 256, 0, stream>>>(vertices, Wt, a, out, Vint, Vnh,
                                            e_center, e_int, e_nh);

    attn_kernel<<<(N_V + 3) / 4, 256, 0, stream>>>(nh_indices, int_indices,
                                                   nh_edges, int_edges, bv,
                                                   Vint, Vnh, e_center, e_int,
                                                   e_nh, out);
}

// Round 3
// 289.306 us; speedup vs baseline: 2.7202x; 1.0503x over previous
//
#include <hip/hip_runtime.h>
#include <stdint.h>

#define N_V 50000
#define F_DIM 128
#define K_DIM 128
#define H_DIM 3
#define M_DIM 10

using bf16x8 = __attribute__((ext_vector_type(8))) short;  // 8 bf16 = 4 VGPRs
using f32x4  = __attribute__((ext_vector_type(4))) float;

__device__ inline unsigned short f2bf(float f) {
    union { float f; uint32_t u; } v; v.f = f;
    uint32_t u = v.u;
    u += 0x7fffu + ((u >> 16) & 1u);   // round-to-nearest-even
    return (unsigned short)(u >> 16);
}

#define LDS_AS __attribute__((address_space(3)))
__device__ inline void gl2lds16(const void* g, void* l) {
    __builtin_amdgcn_global_load_lds(
        (const __attribute__((address_space(1))) unsigned int*)g,
        (LDS_AS unsigned int*)l, 16, 0, 0);
}

// ---------------------------------------------------------------------------
// Kernel 1 (prep): weights (H,F,K) fp32 -> Wt[b][k][f] bf16  (f contiguous),
// plus X fp32 -> Xb bf16 row-major.
// ---------------------------------------------------------------------------
#define WTOT (9 * 128 * 128)
#define XCH  (N_V * 16)          /* 8-element chunks of X */

__global__ void prep(const float* __restrict__ Wvc,
                     const float* __restrict__ Wvn_int,
                     const float* __restrict__ Wvn_nh,
                     const float* __restrict__ X,
                     unsigned short* __restrict__ Wt,
                     unsigned short* __restrict__ Xb) {
    int idx = blockIdx.x * 256 + threadIdx.x;
    if (idx < WTOT) {
        int b   = idx >> 14;
        int rem = idx & 16383;
        int k = rem >> 7;
        int f = rem & 127;
        int h = b / 3, t = b - 3 * h;
        const float* src = (t == 0) ? Wvc : (t == 1) ? Wvn_int : Wvn_nh;
        Wt[idx] = f2bf(src[(h * 128 + f) * 128 + k]);
        return;
    }
    int xi = idx - WTOT;             // chunk of 8 floats
    if (xi < XCH) {
        const float4* Xv = (const float4*)X;
        float4 v0 = Xv[xi * 2];
        float4 v1 = Xv[xi * 2 + 1];
        uint4 o;
        o.x = (uint32_t)f2bf(v0.x) | ((uint32_t)f2bf(v0.y) << 16);
        o.y = (uint32_t)f2bf(v0.z) | ((uint32_t)f2bf(v0.w) << 16);
        o.z = (uint32_t)f2bf(v1.x) | ((uint32_t)f2bf(v1.y) << 16);
        o.w = (uint32_t)f2bf(v1.z) | ((uint32_t)f2bf(v1.w) << 16);
        *(uint4*)&Xb[(size_t)xi * 8] = o;
    }
}

// ---------------------------------------------------------------------------
// Kernel 2: MFMA GEMM. Grid = (ceil(N/64), 9). Block = 256 thr (4 waves).
// A: 64 rows staged to LDS via global_load_lds (16B), XOR-16 chunk swizzle.
// B: each wave owns 32 cols; 8 B-frags loaded direct from global (L2-hot)
//    and held in registers. Wave computes 4 row-tiles x 2 col-tiles.
// Epilogue: t==0 -> Zc fp32 into d_out + e_center; t==1/2 -> V bf16 + e_*.
// ---------------------------------------------------------------------------
__global__ __launch_bounds__(256, 3) void gemm_kernel(
    const unsigned short* __restrict__ Xb,  // N_V x 128 bf16
    const unsigned short* __restrict__ Wt,  // 9 x 128(k) x 128(f) bf16
    const float* __restrict__ a,            // H x 256
    float* __restrict__ out,                // N_V x 384
    unsigned short* __restrict__ Vint,      // H*N_V*128 bf16
    unsigned short* __restrict__ Vnh,       // H*N_V*128 bf16
    float* __restrict__ e_center,           // H*N_V
    float* __restrict__ e_int,
    float* __restrict__ e_nh) {
    __shared__ unsigned short As[64 * 128];   // 16 KB, swizzled
    __shared__ float red[64 * 4];             // cross-wave e-dot partials

    const int tid    = threadIdx.x;
    const int b      = blockIdx.y;
    const int h      = b / 3;
    const int t      = b - 3 * h;
    const int m_base = blockIdx.x * 64;
    const int wv     = tid >> 6;
    const int lane   = tid & 63;
    const int q      = lane >> 4;
    const int ln     = lane & 15;

    // ---- B fragments: direct global loads, kept in registers (32 VGPRs)
    const unsigned short* Wb = Wt + b * 16384;
    bf16x8 bfr[2][4];
    #pragma unroll
    for (int ct = 0; ct < 2; ++ct) {
        int col = wv * 32 + ct * 16 + ln;
        #pragma unroll
        for (int kk = 0; kk < 4; ++kk)
            bfr[ct][kk] = *(const bf16x8*)&Wb[col * 128 + kk * 32 + q * 8];
    }

    // ---- A staging: 1024 chunks of 16B. dest = linear tid*16 (wave-uniform
    // base + lane*16). physical chunk p holds logical chunk p ^ (row & 15).
    #pragma unroll
    for (int it = 0; it < 4; ++it) {
        int c16 = it * 256 + tid;       // 0..1023
        int r   = c16 >> 4;             // row 0..63
        int p   = c16 & 15;             // physical chunk in row
        int lch = p ^ (r & 15);         // logical chunk to fetch
        int gr  = m_base + r;
        if (gr >= N_V) gr = 0;          // clamp (results discarded later)
        gl2lds16(Xb + (size_t)gr * 128 + lch * 8, &As[c16 * 8]);
    }
    __syncthreads();

    // ---- MFMA: wave w -> cols [w*32, w*32+32), rows all 64 (4 tiles of 16)
    f32x4 acc[4][2];
    #pragma unroll
    for (int rt = 0; rt < 4; ++rt)
        #pragma unroll
        for (int ct = 0; ct < 2; ++ct) acc[rt][ct] = (f32x4){0.f, 0.f, 0.f, 0.f};

    #pragma unroll
    for (int rt = 0; rt < 4; ++rt) {
        int r = rt * 16 + ln;
        #pragma unroll
        for (int kk = 0; kk < 4; ++kk) {
            int p = (kk * 4 + q) ^ ln;   // unswizzle: row & 15 == ln
            bf16x8 afr = *(const bf16x8*)&As[r * 128 + p * 8];
            acc[rt][0] = __builtin_amdgcn_mfma_f32_16x16x32_bf16(afr, bfr[0][kk], acc[rt][0], 0, 0, 0);
            acc[rt][1] = __builtin_amdgcn_mfma_f32_16x16x32_bf16(afr, bfr[1][kk], acc[rt][1], 0, 0, 0);
        }
    }

    // ---- e-dot: e[n] = sum_col C[n,col]*a_vec[col]. C/D: row=q*4+rg, col=ln.
    const float* a_vec = a + h * 256 + (t == 0 ? 128 : 0);
    float av0 = a_vec[wv * 32 + ln];
    float av1 = a_vec[wv * 32 + 16 + ln];
    #pragma unroll
    for (int rt = 0; rt < 4; ++rt) {
        float dp[4];
        #pragma unroll
        for (int rg = 0; rg < 4; ++rg) {
            float v = acc[rt][0][rg] * av0 + acc[rt][1][rg] * av1;
            #pragma unroll
            for (int off = 1; off < 16; off <<= 1) v += __shfl_xor(v, off, 64);
            dp[rg] = v;
        }
        if (ln == 0) {
            #pragma unroll
            for (int rg = 0; rg < 4; ++rg)
                red[(rt * 16 + q * 4 + rg) * 4 + wv] = dp[rg];
        }
    }
    __syncthreads();
    float* e_arr = (t == 0) ? e_center : (t == 1) ? e_int : e_nh;
    if (tid < 64) {
        int gr = m_base + tid;
        if (gr < N_V)
            e_arr[h * N_V + gr] = red[tid * 4] + red[tid * 4 + 1] +
                                  red[tid * 4 + 2] + red[tid * 4 + 3];
    }

    // ---- stores
    unsigned short* Vside = (t == 1) ? Vint : Vnh;
    #pragma unroll
    for (int rt = 0; rt < 4; ++rt) {
        #pragma unroll
        for (int rg = 0; rg < 4; ++rg) {
            int gr = m_base + rt * 16 + q * 4 + rg;
            if (gr >= N_V) continue;
            #pragma unroll
            for (int ct = 0; ct < 2; ++ct) {
                int col = wv * 32 + ct * 16 + ln;
                float v = acc[rt][ct][rg];
                if (t == 0) out[(size_t)gr * 384 + h * 128 + col] = v;
                else        Vside[((size_t)h * N_V + gr) * 128 + col] = f2bf(v);
            }
        }
    }
}

// ---------------------------------------------------------------------------
// Kernel 3: attention (unchanged from R2). One wave per vertex,
// 4 groups x 16 lanes, dwordx4 row gathers, folded alpha/norm.
// ---------------------------------------------------------------------------
__global__ __launch_bounds__(256) void attn_kernel(
    const int* __restrict__ nh_idx, const int* __restrict__ int_idx,
    const float* __restrict__ nh_edge, const float* __restrict__ int_edge,
    const float* __restrict__ bv,
    const unsigned short* __restrict__ Vint, const unsigned short* __restrict__ Vnh,
    const float* __restrict__ e_center, const float* __restrict__ e_int,
    const float* __restrict__ e_nh,
    float* __restrict__ out) {
    const int wv   = threadIdx.x >> 6;
    const int lane = threadIdx.x & 63;
    const int n    = blockIdx.x * 4 + wv;
    if (n >= N_V) return;
    const int g  = lane >> 4;
    const int gl = lane & 15;

    const bool part = (g <= 1) && (gl < M_DIM);
    int jm = -1; float wm = 0.f;
    if (part) {
        const int*   idx = (g == 0) ? int_idx  : nh_idx;
        const float* ed  = (g == 0) ? int_edge : nh_edge;
        jm = idx[n * M_DIM + gl];
        wm = ed[n * M_DIM + gl];
    }
    const bool  valid = part && (jm >= 0);
    const int   jc    = valid ? jm : 0;
    const float vfl   = valid ? 1.f : 0.f;

    #pragma unroll
    for (int h = 0; h < H_DIM; ++h) {
        float ec = e_center[h * N_V + n];

        float l = -3.0e38f;
        if (part) {
            const float* es = (g == 0) ? (e_int + (size_t)h * N_V)
                                       : (e_nh  + (size_t)h * N_V);
            float e = es[jc];
            l = valid ? (e + ec) * wm : 0.f;
        }
        float mx = l;
        #pragma unroll
        for (int off = 1; off < 16; off <<= 1) mx = fmaxf(mx, __shfl_xor(mx, off, 64));
        float ex = part ? __expf(l - mx) : 0.f;
        float sv = ex, cf = vfl;
        #pragma unroll
        for (int off = 1; off < 16; off <<= 1) {
            sv += __shfl_xor(sv, off, 64);
            cf += __shfl_xor(cf, off, 64);
        }
        float alphap = 0.f;
        if (valid) alphap = ex / (sv * fmaxf(cf, 1.f));

        const unsigned short* Vb = (g < 2) ? (Vint + (size_t)h * N_V * 128)
                                           : (Vnh  + (size_t)h * N_V * 128);
        const int src_base = (g < 2 ? 0 : 16) + (g & 1) * 5;
        float acc[8] = {0.f, 0.f, 0.f, 0.f, 0.f, 0.f, 0.f, 0.f};
        #pragma unroll
        for (int i = 0; i < 5; ++i) {
            int   src = src_base + i;
            int   j   = __shfl(jc, src, 64);
            float al  = __shfl(alphap, src, 64);
            uint4 pv  = *(const uint4*)&Vb[(size_t)j * 128 + gl * 8];
            uint32_t w4[4] = {pv.x, pv.y, pv.z, pv.w};
            #pragma unroll
            for (int c = 0; c < 4; ++c) {
                union { uint32_t u; float f; } lo, hi;
                lo.u = w4[c] << 16;
                hi.u = w4[c] & 0xffff0000u;
                acc[2 * c]     += al * lo.f;
                acc[2 * c + 1] += al * hi.f;
            }
        }
        #pragma unroll
        for (int c = 0; c < 8; ++c) {
            acc[c] += __shfl_xor(acc[c], 16, 64);
            acc[c] += __shfl_xor(acc[c], 32, 64);
        }
        if (g < 2) {
            size_t o = (size_t)n * 384 + h * 128 + gl * 8 + g * 4;
            float4 zc = *(const float4*)&out[o];
            float4 bb = *(const float4*)&bv[h * 128 + gl * 8 + g * 4];
            float4 zn;
            if (g == 0) zn = make_float4(acc[0], acc[1], acc[2], acc[3]);
            else        zn = make_float4(acc[4], acc[5], acc[6], acc[7]);
            float4 r;
            r.x = fmaxf(zc.x + zn.x + bb.x, 0.f);
            r.y = fmaxf(zc.y + zn.y + bb.y, 0.f);
            r.z = fmaxf(zc.z + zn.z + bb.z, 0.f);
            r.w = fmaxf(zc.w + zn.w + bb.w, 0.f);
            *(float4*)&out[o] = r;
        }
    }
}

// ---------------------------------------------------------------------------
extern "C" void kernel_launch(void* const* d_in, const int* in_sizes, int n_in,
                              void* d_out, int out_size, void* d_ws, size_t ws_size,
                              hipStream_t stream) {
    const float* vertices    = (const float*)d_in[0];
    const int*   nh_indices  = (const int*)d_in[1];
    const int*   int_indices = (const int*)d_in[2];
    const float* nh_edges    = (const float*)d_in[3];
    const float* int_edges   = (const float*)d_in[4];
    // d_in[5] is_int: unused by the reference
    const float* Wvc     = (const float*)d_in[6];
    const float* bv      = (const float*)d_in[7];
    const float* Wvn_int = (const float*)d_in[8];
    const float* Wvn_nh  = (const float*)d_in[9];
    const float* a       = (const float*)d_in[10];
    float* out = (float*)d_out;

    char* ws = (char*)d_ws;
    size_t off = 0;
    unsigned short* Wt = (unsigned short*)(ws + off);
    off += (size_t)WTOT * 2;                  off = (off + 255) & ~(size_t)255;
    unsigned short* Xb = (unsigned short*)(ws + off);
    off += (size_t)N_V * 128 * 2;             off = (off + 255) & ~(size_t)255;
    unsigned short* Vint = (unsigned short*)(ws + off);
    off += (size_t)H_DIM * N_V * 128 * 2;     off = (off + 255) & ~(size_t)255;
    unsigned short* Vnh = (unsigned short*)(ws + off);
    off += (size_t)H_DIM * N_V * 128 * 2;     off = (off + 255) & ~(size_t)255;
    float* e_center = (float*)(ws + off);
    off += (size_t)H_DIM * N_V * 4;           off = (off + 255) & ~(size_t)255;
    float* e_int = (float*)(ws + off);
    off += (size_t)H_DIM * N_V * 4;           off = (off + 255) & ~(size_t)255;
    float* e_nh = (float*)(ws + off);
    off += (size_t)H_DIM * N_V * 4;

    int prep_threads = WTOT + XCH;
    prep<<<(prep_threads + 255) / 256, 256, 0, stream>>>(Wvc, Wvn_int, Wvn_nh,
                                                         vertices, Wt, Xb);

    dim3 grid_g((N_V + 63) / 64, 9);
    gemm_kernel<<<grid_g, 256, 0, stream>>>(Xb, Wt, a, out, Vint, Vnh,
                                            e_center, e_int, e_nh);

    attn_kernel<<<(N_V + 3) / 4, 256, 0, stream>>>(nh_indices, int_indices,
                                                   nh_edges, int_edges, bv,
                                                   Vint, Vnh, e_center, e_int,
                                                   e_nh, out);
}

// Round 4
// 287.213 us; speedup vs baseline: 2.7400x; 1.0073x over previous
//
#include <hip/hip_runtime.h>
#include <stdint.h>

#define N_V 50000
#define F_DIM 128
#define K_DIM 128
#define H_DIM 3
#define M_DIM 10

using bf16x8 = __attribute__((ext_vector_type(8))) short;  // 8 bf16 = 4 VGPRs
using f32x4  = __attribute__((ext_vector_type(4))) float;

__device__ inline unsigned short f2bf(float f) {
    union { float f; uint32_t u; } v; v.f = f;
    uint32_t u = v.u;
    u += 0x7fffu + ((u >> 16) & 1u);   // round-to-nearest-even
    return (unsigned short)(u >> 16);
}

#define LDS_AS __attribute__((address_space(3)))
__device__ inline void gl2lds16(const void* g, void* l) {
    __builtin_amdgcn_global_load_lds(
        (const __attribute__((address_space(1))) unsigned int*)g,
        (LDS_AS unsigned int*)l, 16, 0, 0);
}

// ---------------------------------------------------------------------------
// Kernel 1 (prep): three segments.
//  a) weights (H,F,K) fp32 -> Wt[b][k][f] bf16 (f contiguous)
//  b) X fp32 -> Xb bf16 row-major
//  c) wa[b][f] = sum_col W_b[f,col] * a_vec_b[col]  -> bf16  (for e = X*wa)
// ---------------------------------------------------------------------------
#define WTOT (9 * 128 * 128)
#define XCH  (N_V * 16)          /* 8-element chunks of X */
#define WACT (9 * 128)

__global__ void prep(const float* __restrict__ Wvc,
                     const float* __restrict__ Wvn_int,
                     const float* __restrict__ Wvn_nh,
                     const float* __restrict__ X,
                     const float* __restrict__ a,
                     unsigned short* __restrict__ Wt,
                     unsigned short* __restrict__ Xb,
                     unsigned short* __restrict__ wab) {
    int idx = blockIdx.x * 256 + threadIdx.x;
    if (idx < WTOT) {
        int b   = idx >> 14;
        int rem = idx & 16383;
        int k = rem >> 7;
        int f = rem & 127;
        int h = b / 3, t = b - 3 * h;
        const float* src = (t == 0) ? Wvc : (t == 1) ? Wvn_int : Wvn_nh;
        Wt[idx] = f2bf(src[(h * 128 + f) * 128 + k]);
        return;
    }
    int xi = idx - WTOT;             // chunk of 8 floats of X
    if (xi < XCH) {
        const float4* Xv = (const float4*)X;
        float4 v0 = Xv[xi * 2];
        float4 v1 = Xv[xi * 2 + 1];
        uint4 o;
        o.x = (uint32_t)f2bf(v0.x) | ((uint32_t)f2bf(v0.y) << 16);
        o.y = (uint32_t)f2bf(v0.z) | ((uint32_t)f2bf(v0.w) << 16);
        o.z = (uint32_t)f2bf(v1.x) | ((uint32_t)f2bf(v1.y) << 16);
        o.w = (uint32_t)f2bf(v1.z) | ((uint32_t)f2bf(v1.w) << 16);
        *(uint4*)&Xb[(size_t)xi * 8] = o;
        return;
    }
    int wi = xi - XCH;               // wa entry
    if (wi < WACT) {
        int b = wi >> 7, f = wi & 127;
        int h = b / 3, t = b - 3 * h;
        const float* src = (t == 0) ? Wvc : (t == 1) ? Wvn_int : Wvn_nh;
        const float4* wrow = (const float4*)&src[(h * 128 + f) * 128];
        const float4* av   = (const float4*)&a[h * 256 + (t == 0 ? 128 : 0)];
        float acc = 0.f;
        #pragma unroll 8
        for (int c = 0; c < 32; ++c) {
            float4 w = wrow[c], x = av[c];
            acc += w.x * x.x + w.y * x.y + w.z * x.z + w.w * x.w;
        }
        wab[b * 128 + f] = f2bf(acc);
    }
}

// ---------------------------------------------------------------------------
// Kernel 2: MFMA GEMM. Grid = (ceil(N/64), 9). Block = 256 thr (4 waves).
// A: 64 rows staged to LDS via global_load_lds (16B), XOR-16 chunk swizzle.
// B: wave owns 32 cols; frag ct holds col wv*32 + 2*ln + ct so each thread's
//    two accumulators are ADJACENT output columns (pack-2 stores).
// e: wave 0 computes e = A * wa via 16 extra MFMAs (wa in B col 0).
// ---------------------------------------------------------------------------
__global__ __launch_bounds__(256, 3) void gemm_kernel(
    const unsigned short* __restrict__ Xb,  // N_V x 128 bf16
    const unsigned short* __restrict__ Wt,  // 9 x 128(k) x 128(f) bf16
    const unsigned short* __restrict__ wab, // 9 x 128 bf16
    float* __restrict__ out,                // N_V x 384
    unsigned short* __restrict__ Vint,      // H*N_V*128 bf16
    unsigned short* __restrict__ Vnh,       // H*N_V*128 bf16
    float* __restrict__ e_center,           // H*N_V
    float* __restrict__ e_int,
    float* __restrict__ e_nh) {
    __shared__ unsigned short As[64 * 128];   // 16 KB, swizzled

    const int tid    = threadIdx.x;
    const int b      = blockIdx.y;
    const int h      = b / 3;
    const int t      = b - 3 * h;
    const int m_base = blockIdx.x * 64;
    const int wv     = tid >> 6;
    const int lane   = tid & 63;
    const int q      = lane >> 4;
    const int ln     = lane & 15;

    // ---- B fragments (direct global, L2-hot). col = wv*32 + 2*ln + ct.
    const unsigned short* Wb = Wt + b * 16384;
    bf16x8 bfr[2][4];
    #pragma unroll
    for (int ct = 0; ct < 2; ++ct) {
        int col = wv * 32 + 2 * ln + ct;
        #pragma unroll
        for (int kk = 0; kk < 4; ++kk)
            bfr[ct][kk] = *(const bf16x8*)&Wb[col * 128 + kk * 32 + q * 8];
    }

    // ---- A staging: 1024 chunks of 16B. physical chunk p of row r holds
    // logical chunk p ^ (r & 15); dest = wave-uniform base + lane*16.
    #pragma unroll
    for (int it = 0; it < 4; ++it) {
        int c16 = it * 256 + tid;       // 0..1023
        int r   = c16 >> 4;
        int p   = c16 & 15;
        int lch = p ^ (r & 15);
        int gr  = m_base + r;
        if (gr >= N_V) gr = 0;          // clamp (stores guarded later)
        gl2lds16(Xb + (size_t)gr * 128 + lch * 8, &As[c16 * 8]);
    }
    __syncthreads();

    // ---- main MFMA: wave w -> 32 cols, rows all 64 (4 tiles of 16)
    f32x4 acc[4][2];
    #pragma unroll
    for (int rt = 0; rt < 4; ++rt)
        #pragma unroll
        for (int ct = 0; ct < 2; ++ct) acc[rt][ct] = (f32x4){0.f, 0.f, 0.f, 0.f};

    #pragma unroll
    for (int rt = 0; rt < 4; ++rt) {
        int r = rt * 16 + ln;
        #pragma unroll
        for (int kk = 0; kk < 4; ++kk) {
            int p = (kk * 4 + q) ^ ln;   // unswizzle (r & 15 == ln)
            bf16x8 afr = *(const bf16x8*)&As[r * 128 + p * 8];
            acc[rt][0] = __builtin_amdgcn_mfma_f32_16x16x32_bf16(afr, bfr[0][kk], acc[rt][0], 0, 0, 0);
            acc[rt][1] = __builtin_amdgcn_mfma_f32_16x16x32_bf16(afr, bfr[1][kk], acc[rt][1], 0, 0, 0);
        }
    }

    // ---- e = A * wa  (wave 0 only; B col 0 = wa, cols 1..15 = 0)
    if (wv == 0) {
        bf16x8 wz[4];
        #pragma unroll
        for (int kk = 0; kk < 4; ++kk) {
            bf16x8 z = {0, 0, 0, 0, 0, 0, 0, 0};
            if (ln == 0) z = *(const bf16x8*)&wab[b * 128 + kk * 32 + q * 8];
            wz[kk] = z;
        }
        float* e_arr = (t == 0) ? e_center : (t == 1) ? e_int : e_nh;
        #pragma unroll
        for (int rt = 0; rt < 4; ++rt) {
            int r = rt * 16 + ln;
            f32x4 ae = (f32x4){0.f, 0.f, 0.f, 0.f};
            #pragma unroll
            for (int kk = 0; kk < 4; ++kk) {
                int p = (kk * 4 + q) ^ ln;
                bf16x8 afr = *(const bf16x8*)&As[r * 128 + p * 8];
                ae = __builtin_amdgcn_mfma_f32_16x16x32_bf16(afr, wz[kk], ae, 0, 0, 0);
            }
            if (ln == 0) {
                #pragma unroll
                for (int rg = 0; rg < 4; ++rg) {
                    int gr = m_base + rt * 16 + q * 4 + rg;
                    if (gr < N_V) e_arr[h * N_V + gr] = ae[rg];
                }
            }
        }
    }

    // ---- stores: thread owns adjacent cols c0 = wv*32 + 2*ln, c0+1.
    const int c0 = wv * 32 + 2 * ln;
    if (t == 0) {
        #pragma unroll
        for (int rt = 0; rt < 4; ++rt)
            #pragma unroll
            for (int rg = 0; rg < 4; ++rg) {
                int gr = m_base + rt * 16 + q * 4 + rg;
                if (gr >= N_V) continue;
                float2 v = make_float2(acc[rt][0][rg], acc[rt][1][rg]);
                *(float2*)&out[(size_t)gr * 384 + h * 128 + c0] = v;
            }
    } else {
        unsigned short* Vside = (t == 1) ? Vint : Vnh;
        #pragma unroll
        for (int rt = 0; rt < 4; ++rt)
            #pragma unroll
            for (int rg = 0; rg < 4; ++rg) {
                int gr = m_base + rt * 16 + q * 4 + rg;
                if (gr >= N_V) continue;
                uint32_t pk = (uint32_t)f2bf(acc[rt][0][rg]) |
                              ((uint32_t)f2bf(acc[rt][1][rg]) << 16);
                *(uint32_t*)&Vside[((size_t)h * N_V + gr) * 128 + c0] = pk;
            }
    }
}

// ---------------------------------------------------------------------------
// Kernel 3: attention (unchanged from R2). One wave per vertex,
// 4 groups x 16 lanes, dwordx4 row gathers, folded alpha/norm.
// ---------------------------------------------------------------------------
__global__ __launch_bounds__(256) void attn_kernel(
    const int* __restrict__ nh_idx, const int* __restrict__ int_idx,
    const float* __restrict__ nh_edge, const float* __restrict__ int_edge,
    const float* __restrict__ bv,
    const unsigned short* __restrict__ Vint, const unsigned short* __restrict__ Vnh,
    const float* __restrict__ e_center, const float* __restrict__ e_int,
    const float* __restrict__ e_nh,
    float* __restrict__ out) {
    const int wv   = threadIdx.x >> 6;
    const int lane = threadIdx.x & 63;
    const int n    = blockIdx.x * 4 + wv;
    if (n >= N_V) return;
    const int g  = lane >> 4;
    const int gl = lane & 15;

    const bool part = (g <= 1) && (gl < M_DIM);
    int jm = -1; float wm = 0.f;
    if (part) {
        const int*   idx = (g == 0) ? int_idx  : nh_idx;
        const float* ed  = (g == 0) ? int_edge : nh_edge;
        jm = idx[n * M_DIM + gl];
        wm = ed[n * M_DIM + gl];
    }
    const bool  valid = part && (jm >= 0);
    const int   jc    = valid ? jm : 0;
    const float vfl   = valid ? 1.f : 0.f;

    #pragma unroll
    for (int h = 0; h < H_DIM; ++h) {
        float ec = e_center[h * N_V + n];

        float l = -3.0e38f;
        if (part) {
            const float* es = (g == 0) ? (e_int + (size_t)h * N_V)
                                       : (e_nh  + (size_t)h * N_V);
            float e = es[jc];
            l = valid ? (e + ec) * wm : 0.f;
        }
        float mx = l;
        #pragma unroll
        for (int off = 1; off < 16; off <<= 1) mx = fmaxf(mx, __shfl_xor(mx, off, 64));
        float ex = part ? __expf(l - mx) : 0.f;
        float sv = ex, cf = vfl;
        #pragma unroll
        for (int off = 1; off < 16; off <<= 1) {
            sv += __shfl_xor(sv, off, 64);
            cf += __shfl_xor(cf, off, 64);
        }
        float alphap = 0.f;
        if (valid) alphap = ex / (sv * fmaxf(cf, 1.f));

        const unsigned short* Vb = (g < 2) ? (Vint + (size_t)h * N_V * 128)
                                           : (Vnh  + (size_t)h * N_V * 128);
        const int src_base = (g < 2 ? 0 : 16) + (g & 1) * 5;
        float acc[8] = {0.f, 0.f, 0.f, 0.f, 0.f, 0.f, 0.f, 0.f};
        #pragma unroll
        for (int i = 0; i < 5; ++i) {
            int   src = src_base + i;
            int   j   = __shfl(jc, src, 64);
            float al  = __shfl(alphap, src, 64);
            uint4 pv  = *(const uint4*)&Vb[(size_t)j * 128 + gl * 8];
            uint32_t w4[4] = {pv.x, pv.y, pv.z, pv.w};
            #pragma unroll
            for (int c = 0; c < 4; ++c) {
                union { uint32_t u; float f; } lo, hi;
                lo.u = w4[c] << 16;
                hi.u = w4[c] & 0xffff0000u;
                acc[2 * c]     += al * lo.f;
                acc[2 * c + 1] += al * hi.f;
            }
        }
        #pragma unroll
        for (int c = 0; c < 8; ++c) {
            acc[c] += __shfl_xor(acc[c], 16, 64);
            acc[c] += __shfl_xor(acc[c], 32, 64);
        }
        if (g < 2) {
            size_t o = (size_t)n * 384 + h * 128 + gl * 8 + g * 4;
            float4 zc = *(const float4*)&out[o];
            float4 bb = *(const float4*)&bv[h * 128 + gl * 8 + g * 4];
            float4 zn;
            if (g == 0) zn = make_float4(acc[0], acc[1], acc[2], acc[3]);
            else        zn = make_float4(acc[4], acc[5], acc[6], acc[7]);
            float4 r;
            r.x = fmaxf(zc.x + zn.x + bb.x, 0.f);
            r.y = fmaxf(zc.y + zn.y + bb.y, 0.f);
            r.z = fmaxf(zc.z + zn.z + bb.z, 0.f);
            r.w = fmaxf(zc.w + zn.w + bb.w, 0.f);
            *(float4*)&out[o] = r;
        }
    }
}

// ---------------------------------------------------------------------------
extern "C" void kernel_launch(void* const* d_in, const int* in_sizes, int n_in,
                              void* d_out, int out_size, void* d_ws, size_t ws_size,
                              hipStream_t stream) {
    const float* vertices    = (const float*)d_in[0];
    const int*   nh_indices  = (const int*)d_in[1];
    const int*   int_indices = (const int*)d_in[2];
    const float* nh_edges    = (const float*)d_in[3];
    const float* int_edges   = (const float*)d_in[4];
    // d_in[5] is_int: unused by the reference
    const float* Wvc     = (const float*)d_in[6];
    const float* bv      = (const float*)d_in[7];
    const float* Wvn_int = (const float*)d_in[8];
    const float* Wvn_nh  = (const float*)d_in[9];
    const float* a       = (const float*)d_in[10];
    float* out = (float*)d_out;

    char* ws = (char*)d_ws;
    size_t off = 0;
    unsigned short* Wt = (unsigned short*)(ws + off);
    off += (size_t)WTOT * 2;                  off = (off + 255) & ~(size_t)255;
    unsigned short* wab = (unsigned short*)(ws + off);
    off += (size_t)WACT * 2;                  off = (off + 255) & ~(size_t)255;
    unsigned short* Xb = (unsigned short*)(ws + off);
    off += (size_t)N_V * 128 * 2;             off = (off + 255) & ~(size_t)255;
    unsigned short* Vint = (unsigned short*)(ws + off);
    off += (size_t)H_DIM * N_V * 128 * 2;     off = (off + 255) & ~(size_t)255;
    unsigned short* Vnh = (unsigned short*)(ws + off);
    off += (size_t)H_DIM * N_V * 128 * 2;     off = (off + 255) & ~(size_t)255;
    float* e_center = (float*)(ws + off);
    off += (size_t)H_DIM * N_V * 4;           off = (off + 255) & ~(size_t)255;
    float* e_int = (float*)(ws + off);
    off += (size_t)H_DIM * N_V * 4;           off = (off + 255) & ~(size_t)255;
    float* e_nh = (float*)(ws + off);
    off += (size_t)H_DIM * N_V * 4;

    int prep_threads = WTOT + XCH + WACT;
    prep<<<(prep_threads + 255) / 256, 256, 0, stream>>>(
        Wvc, Wvn_int, Wvn_nh, vertices, a, Wt, Xb, wab);

    dim3 grid_g((N_V + 63) / 64, 9);
    gemm_kernel<<<grid_g, 256, 0, stream>>>(Xb, Wt, wab, out, Vint, Vnh,
                                            e_center, e_int, e_nh);

    attn_kernel<<<(N_V + 3) / 4, 256, 0, stream>>>(nh_indices, int_indices,
                                                   nh_edges, int_edges, bv,
                                                   Vint, Vnh, e_center, e_int,
                                                   e_nh, out);
}